// Round 4
// baseline (12980.098 us; speedup 1.0000x reference)
//
#include <hip/hip_runtime.h>

#define BATCH    16384
#define H_DIM    1024
#define D_DIM    512
#define O_DIM    10
#define SEQ      128
#define BM       64
#define NTHREADS 512
#define LSTR     1032   // bf16 elements per LDS row (1024 + 8 pad)

typedef __bf16 bf16;
typedef __bf16 bf16x8 __attribute__((ext_vector_type(8)));
typedef float  f32x16 __attribute__((ext_vector_type(16)));
typedef float  f32x4  __attribute__((ext_vector_type(4)));

// ---- static device buffers: fp32 inputs converted once to bf16 ----
__device__ bf16  g_x[BATCH * D_DIM];     // 16 MB
__device__ bf16  g_whx[H_DIM * D_DIM];   // 1 MB
__device__ bf16  g_whh[H_DIM * H_DIM];   // 2 MB
__device__ bf16  g_wph[O_DIM * H_DIM];   // 20 KB
__device__ float g_bias[H_DIM];          // Whx_b + Whh_b combined
__device__ float g_bph[O_DIM];

__device__ __forceinline__ float fast_tanh(float z) {
  // tanh(z) = 1 - 2/(exp(2z)+1); exact at +-inf, NaN-free for finite z
  float e = __expf(2.0f * z);
  return 1.0f - 2.0f / (e + 1.0f);
}

// ---- fp32 -> bf16 conversion (8 elems/thread, vectorized) ----
__global__ void cvt_bf16(const float* __restrict__ src, bf16* __restrict__ dst, int n) {
  const int i = (blockIdx.x * blockDim.x + threadIdx.x) * 8;
  if (i >= n) return;
  f32x4 s0 = *(const f32x4*)(src + i);
  f32x4 s1 = *(const f32x4*)(src + i + 4);
  bf16x8 v;
  #pragma unroll
  for (int j = 0; j < 4; ++j) { v[j] = (bf16)s0[j]; v[4 + j] = (bf16)s1[j]; }
  *(bf16x8*)(dst + i) = v;
}

// ---- biases: Whx_b + Whh_b combined; Wph_b copied (all fp32) ----
__global__ void cvt_bias(const float* __restrict__ bx, const float* __restrict__ bh,
                         const float* __restrict__ bp) {
  const int i = blockIdx.x * blockDim.x + threadIdx.x;
  if (i < H_DIM) g_bias[i] = bx[i] + bh[i];
  if (i < O_DIM) g_bph[i]  = bp[i];
}

// One block owns BM=64 batch rows for the whole 128-step sequence.
// 8 waves; wave tile = 64 rows x 128 cols; mfma_f32_32x32x16_bf16.
// h tile in LDS (bf16, padded stride). g_whh streams from L2 each step.
// xW + biases (loop-invariant) lives in registers as packed bf16.
// NOTE: A/B fragments use identical lane->k indexing, so any k-permutation
// cancels between A and B; only the C/D mapping (HW-verified m74/m101)
// and lane&31 m/n mapping must be exact.
__global__ __launch_bounds__(NTHREADS, 2)
void rnn_fused(float* __restrict__ out)
{
  extern __shared__ char smem[];
  bf16* hbuf = (bf16*)smem;

  const int tid  = threadIdx.x;
  const int wave = tid >> 6;
  const int lane = tid & 63;
  const int m31  = lane & 31;   // A/B fragment row/col within 32
  const int q    = lane >> 5;   // k half-group: k in [8q, 8q+8)
  const int r0   = blockIdx.x * BM;
  const int nw0  = wave * 128;  // this wave's output-column range

  f32x16 acc[2][4];
  bf16x8 xw[2][4][2];           // loop-invariant xW+biases, acc-aligned layout

  // ---------------- Phase 0: xwb = x @ Whx^T + bhx + bhh; h1 = tanh(xwb) ----------------
  #pragma unroll
  for (int mt = 0; mt < 2; ++mt)
    #pragma unroll
    for (int nt = 0; nt < 4; ++nt)
      #pragma unroll
      for (int i = 0; i < 16; ++i) acc[mt][nt][i] = 0.0f;

  {
    const bf16* aBase = g_x + (size_t)(r0 + m31) * D_DIM + q * 8;
    #pragma unroll 4
    for (int kc = 0; kc < D_DIM / 16; ++kc) {
      bf16x8 a[2], b[4];
      #pragma unroll
      for (int mt = 0; mt < 2; ++mt)
        a[mt] = *(const bf16x8*)(aBase + (size_t)mt * 32 * D_DIM + kc * 16);
      #pragma unroll
      for (int nt = 0; nt < 4; ++nt)
        b[nt] = *(const bf16x8*)(g_whx + (size_t)(nw0 + nt * 32 + m31) * D_DIM + kc * 16 + q * 8);
      #pragma unroll
      for (int mt = 0; mt < 2; ++mt)
        #pragma unroll
        for (int nt = 0; nt < 4; ++nt)
          acc[mt][nt] = __builtin_amdgcn_mfma_f32_32x32x16_bf16(a[mt], b[nt], acc[mt][nt], 0, 0, 0);
    }
  }

  #pragma unroll
  for (int nt = 0; nt < 4; ++nt) {
    const int col = nw0 + nt * 32 + m31;
    const float bias = g_bias[col];
    #pragma unroll
    for (int mt = 0; mt < 2; ++mt)
      #pragma unroll
      for (int r = 0; r < 16; ++r) {
        const int row = mt * 32 + (r & 3) + 8 * (r >> 2) + 4 * q;  // C/D layout (m74/m101)
        const float v = acc[mt][nt][r] + bias;
        xw[mt][nt][r >> 3][r & 7] = (bf16)v;
        hbuf[row * LSTR + col] = (bf16)fast_tanh(v);   // h after step 1 (h0 = 0)
      }
  }
  __syncthreads();

  // ---------------- RNN steps 2..SEQ ----------------
  for (int step = 1; step < SEQ; ++step) {
    #pragma unroll
    for (int mt = 0; mt < 2; ++mt)
      #pragma unroll
      for (int nt = 0; nt < 4; ++nt)
        #pragma unroll
        for (int i = 0; i < 16; ++i) acc[mt][nt][i] = 0.0f;

    #pragma unroll 4
    for (int kc = 0; kc < H_DIM / 16; ++kc) {
      bf16x8 a[2], b[4];
      #pragma unroll
      for (int mt = 0; mt < 2; ++mt)
        a[mt] = *(const bf16x8*)(hbuf + (32 * mt + m31) * LSTR + kc * 16 + q * 8);
      #pragma unroll
      for (int nt = 0; nt < 4; ++nt)
        b[nt] = *(const bf16x8*)(g_whh + (size_t)(nw0 + nt * 32 + m31) * H_DIM + kc * 16 + q * 8);
      #pragma unroll
      for (int mt = 0; mt < 2; ++mt)
        #pragma unroll
        for (int nt = 0; nt < 4; ++nt)
          acc[mt][nt] = __builtin_amdgcn_mfma_f32_32x32x16_bf16(a[mt], b[nt], acc[mt][nt], 0, 0, 0);
    }

    __syncthreads();   // all waves finished READING hbuf

    #pragma unroll
    for (int nt = 0; nt < 4; ++nt) {
      const int col = nw0 + nt * 32 + m31;
      #pragma unroll
      for (int mt = 0; mt < 2; ++mt)
        #pragma unroll
        for (int r = 0; r < 16; ++r) {
          const int row = mt * 32 + (r & 3) + 8 * (r >> 2) + 4 * q;
          const float xv = (float)xw[mt][nt][r >> 3][r & 7];
          hbuf[row * LSTR + col] = (bf16)fast_tanh(acc[mt][nt][r] + xv);
        }
    }
    __syncthreads();   // new h visible to all waves
  }

  // ---------------- Output head: softmax(h @ Wph^T + b), fp32 out ----------------
  {
    const int row  = tid >> 3;   // 0..63
    const int tsub = tid & 7;    // 8 threads per row, k-partitioned
    float p[O_DIM];
    #pragma unroll
    for (int o = 0; o < O_DIM; ++o) p[o] = 0.0f;

    const bf16* hrow = hbuf + row * LSTR;
    const int k0 = tsub * 128;
    for (int kk = 0; kk < 128; kk += 8) {
      bf16x8 hv = *(const bf16x8*)(hrow + k0 + kk);
      float hf[8];
      #pragma unroll
      for (int j = 0; j < 8; ++j) hf[j] = (float)hv[j];
      #pragma unroll
      for (int o = 0; o < O_DIM; ++o) {
        bf16x8 wv = *(const bf16x8*)(g_wph + (size_t)o * H_DIM + k0 + kk);
        #pragma unroll
        for (int j = 0; j < 8; ++j) p[o] += hf[j] * (float)wv[j];
      }
    }
    #pragma unroll
    for (int d = 1; d < 8; d <<= 1)
      #pragma unroll
      for (int o = 0; o < O_DIM; ++o) p[o] += __shfl_xor(p[o], d, 8);

    if (tsub == 0) {
      float v[O_DIM], mx = -1e30f;
      #pragma unroll
      for (int o = 0; o < O_DIM; ++o) { v[o] = p[o] + g_bph[o]; mx = fmaxf(mx, v[o]); }
      float s = 0.0f;
      #pragma unroll
      for (int o = 0; o < O_DIM; ++o) { v[o] = __expf(v[o] - mx); s += v[o]; }
      const float inv = 1.0f / s;
      #pragma unroll
      for (int o = 0; o < O_DIM; ++o)
        out[(size_t)(r0 + row) * O_DIM + o] = v[o] * inv;   // fp32 (reference output dtype)
    }
  }
}

extern "C" void kernel_launch(void* const* d_in, const int* in_sizes, int n_in,
                              void* d_out, int out_size, void* d_ws, size_t ws_size,
                              hipStream_t stream)
{
  (void)d_ws; (void)ws_size; (void)in_sizes; (void)n_in; (void)out_size;
  const float* x     = (const float*)d_in[0];
  const float* Whx_w = (const float*)d_in[1];
  const float* Whx_b = (const float*)d_in[2];
  const float* Whh_w = (const float*)d_in[3];
  const float* Whh_b = (const float*)d_in[4];
  const float* Wph_w = (const float*)d_in[5];
  const float* Wph_b = (const float*)d_in[6];
  float* out = (float*)d_out;

  // Allow >64KB dynamic LDS (defensive; 132KB worked in prior rounds too).
  (void)hipFuncSetAttribute((const void*)rnn_fused,
                            hipFuncAttributeMaxDynamicSharedMemorySize, 132096);

  // 1) convert fp32 inputs -> bf16 static buffers
  bf16* gx; bf16* gwhx; bf16* gwhh; bf16* gwph;
  hipGetSymbolAddress((void**)&gx,   HIP_SYMBOL(g_x));
  hipGetSymbolAddress((void**)&gwhx, HIP_SYMBOL(g_whx));
  hipGetSymbolAddress((void**)&gwhh, HIP_SYMBOL(g_whh));
  hipGetSymbolAddress((void**)&gwph, HIP_SYMBOL(g_wph));
  cvt_bf16<<<BATCH * D_DIM / 2048, 256, 0, stream>>>(x,     gx,   BATCH * D_DIM);
  cvt_bf16<<<H_DIM * D_DIM / 2048, 256, 0, stream>>>(Whx_w, gwhx, H_DIM * D_DIM);
  cvt_bf16<<<H_DIM * H_DIM / 2048, 256, 0, stream>>>(Whh_w, gwhh, H_DIM * H_DIM);
  cvt_bf16<<<(O_DIM * H_DIM / 8 + 255) / 256, 256, 0, stream>>>(Wph_w, gwph, O_DIM * H_DIM);
  cvt_bias<<<4, 256, 0, stream>>>(Whx_b, Whh_b, Wph_b);

  // 2) fused RNN (one launch, no grid sync needed: blocks own disjoint rows)
  const dim3 grid(BATCH / BM), block(NTHREADS);
  const size_t lds = (size_t)BM * LSTR * sizeof(bf16);   // 132096 B
  rnn_fused<<<grid, block, lds, stream>>>(out);
}